// Round 12
// baseline (269.722 us; speedup 1.0000x reference)
//
#include <hip/hip_runtime.h>

// ---------------------------------------------------------------------------
// 2-layer GAT (PyG GATConv), MI355X.
// R33 (from R32 = 249.7us best; fused kernel now 80-90us with MfmaUtil 1.3%
//      -> it IS the histogram, and hist runs SLOWER next to the gemm's
//      L2-heavy staging than next to streaming work (R26: prep+hist = 50us)):
//   RE-PARTNER the hist: fuse with k_prep (streaming), un-fuse from gemm1.
//   (1) k_prep_hist: HIST blocks first (0 LDS, resident at t=0, start the
//       ~40-50us atomic phase immediately); W-prep + x->bf16 stream under.
//       Keeps R30's 8-deep two-phase hist + padded-adj scattered stores.
//   (2) k_gemm1: pure 1-term gemm, 784 blocks, 32KB LDS -- no co-resident
//       atomics inflating its staging latency.
//   (3) cnt zeroing back to hipMemsetAsync (no zero/hist race in-kernel).
//   (4) aggr1 / gemm2 / aggr2 byte-frozen from R32.
//   6 launches: memset, prep_hist, gemm1, aggr1, gemm2, aggr2.
// ---------------------------------------------------------------------------

typedef __attribute__((ext_vector_type(8))) short short8;
typedef __attribute__((ext_vector_type(4))) float f32x4;
typedef __attribute__((ext_vector_type(2))) float f32x2;

static __device__ __forceinline__ ushort f2bf(float f) {  // RNE
  uint u = __float_as_uint(f);
  return (ushort)((u + 0x7FFFu + ((u >> 16) & 1u)) >> 16);
}
static __device__ __forceinline__ float bf2f(ushort s) {
  return __uint_as_float(((uint)s) << 16);
}
static __device__ __forceinline__ unsigned char f2fp8(float f) {  // e4m3 (HW)
  int p = __builtin_amdgcn_cvt_pk_fp8_f32(f, f, 0, false);
  return (unsigned char)(p & 0xFF);
}
static __device__ __forceinline__ uint4 cvt8bf(const float4& a, const float4& b) {
  uint4 hh;
  hh.x = (uint)f2bf(a.x) | ((uint)f2bf(a.y) << 16);
  hh.y = (uint)f2bf(a.z) | ((uint)f2bf(a.w) << 16);
  hh.z = (uint)f2bf(b.x) | ((uint)f2bf(b.y) << 16);
  hh.w = (uint)f2bf(b.z) | ((uint)f2bf(b.w) << 16);
  return hh;
}
// async global->LDS, 16B per lane (wave-uniform LDS base + lane*16)
static __device__ __forceinline__ void gl16(const ushort* g, ushort* l) {
  __builtin_amdgcn_global_load_lds(
      (const __attribute__((address_space(1))) uint*)(g),
      (__attribute__((address_space(3))) uint*)(l), 16, 0, 0);
}

// ---- fused: HIST blocks first, then W-prep + x->bf16 (streaming) ----------
// Hist: 8 edges/thread (2048/block). Phase A: coalesced dst/src loads.
// Phase B: 8 atomicAdds issued back-to-back (returns pipelined).
// Phase C: 8 scattered col2 stores (col2[(dst<<6)+slot] = src<<8).
// cnt pre-zeroed by hipMemsetAsync (stream-ordered before this kernel).
__global__ __launch_bounds__(256)
void k_prep_hist(const float* __restrict__ W1, const float* __restrict__ W2,
                 ushort* __restrict__ w1t, ushort* __restrict__ w2t,
                 const float* __restrict__ x, ushort* __restrict__ xb,
                 const int* __restrict__ srcv, const int* __restrict__ dstv,
                 int* __restrict__ cnt, int* __restrict__ col2,
                 int E, int ng, int eb8) {
  const int b = blockIdx.x;
  if (b < eb8) {  // histogram + padded-adjacency scatter
    int base = b * 2048 + threadIdx.x;
    int d[8], v[8], s[8];
#pragma unroll
    for (int k = 0; k < 8; k++) {
      int i = base + k * 256;
      bool ok = i < E;
      d[k] = ok ? dstv[i] : 0;
      v[k] = ok ? (srcv[i] << 8) : 0;
    }
#pragma unroll
    for (int k = 0; k < 8; k++) {
      int i = base + k * 256;
      s[k] = (i < E) ? atomicAdd(&cnt[d[k]], 1) : 64;
    }
#pragma unroll
    for (int k = 0; k < 8; k++) {
      int i = base + k * 256;
      if (i < E && s[k] < 64) col2[(d[k] << 6) + s[k]] = v[k];
    }
  } else if (b < eb8 + 128) {  // W1 [128][256] -> [256][128] bf16
    int gid = (b - eb8) * 256 + threadIdx.x;
    int c = gid & 255, k = gid >> 8;
    w1t[(size_t)c * 128 + k] = f2bf(W1[(size_t)k * 256 + c]);
  } else if (b < eb8 + 384) {  // W2 [256][256] -> [256][256] bf16
    int gid = (b - eb8 - 128) * 256 + threadIdx.x;
    int c = gid & 255, k = gid >> 8;
    w2t[(size_t)c * 256 + k] = f2bf(W2[(size_t)k * 256 + c]);
  } else {  // x fp32 -> bf16 (RNE), 8 elems/thread
    int i = (b - eb8 - 384) * 256 + threadIdx.x;
    if (i < ng) {
      const float4* xp = (const float4*)x + (size_t)i * 2;
      float4 a = xp[0], bb = xp[1];
      ((uint4*)xb)[i] = cvt8bf(a, bb);
    }
  }
}

// ----------------------------- MFMA GEMM body ------------------------------
// 256 threads / 4 waves; block tile 128 rows x 128 cols (col-half of C).
// Wave tile 64x64: wr=(w>>1)*64, wc=(w&1)*64; acc[4][4].
// Async-staged double-buffered LDS via global_load_lds; one __syncthreads
// per K-step; next stage issued right after the barrier. Single-term
// (plain bf16 W): A + B tiles only, LDS 32KB -> 5 blocks/CU.
// C[N,256] = A_bf16 @ B[K,256], Bt stored [256][K]. C -> FP8 e4m3.
// XCD-aligned swizzle: col-halves of a row block differ by 8 block ids.
template <int K>
static __device__ __forceinline__
void gemm_body(int bid, const ushort* __restrict__ Ah,
               const ushort* __restrict__ Bt,
               unsigned char* __restrict__ hout, int Nrows,
               const float* __restrict__ att_s, const float* __restrict__ att_d,
               float* __restrict__ a_s, float* __restrict__ a_d) {
  __shared__ ushort Asb[2][128][32];
  __shared__ ushort Bhb[2][128][32];

  const int nrb = (Nrows + 127) >> 7;
  const int rb = (bid >> 4) * 8 + (bid & 7);
  const int ch = (bid >> 3) & 1;
  if (rb >= nrb) return;
  const int row0 = rb * 128;
  const int col0 = ch * 128;

  const int t = threadIdx.x;
  const int lane = t & 63;
  const int w = t >> 6;            // 0..3
  const int wr = (w >> 1) * 64;
  const int wc = (w & 1) * 64;
  const int fr = lane & 15;
  const int fq = lane >> 4;

  // staging source addresses (per-lane)
  const int srow = lane >> 2;          // 0..15
  const int skc = (lane & 3) * 8;      // k offset in elems
  int ar0 = row0 + w * 32 + srow;
  int ar1 = ar0 + 16;
  ar0 = ar0 < Nrows ? ar0 : Nrows - 1;  // clamped tail (stores guarded later)
  ar1 = ar1 < Nrows ? ar1 : Nrows - 1;
  const ushort* agp0 = Ah + (size_t)ar0 * K + skc;
  const ushort* agp1 = Ah + (size_t)ar1 * K + skc;
  const ushort* bhg0 = Bt + (size_t)(col0 + w * 32 + srow) * K + skc;
  const ushort* bhg1 = bhg0 + (size_t)16 * K;

  f32x4 acc[4][4] = {};

  auto stage = [&](int buf, int k0) {
    gl16(agp0 + k0, &Asb[buf][w * 32][0]);
    gl16(agp1 + k0, &Asb[buf][w * 32 + 16][0]);
    gl16(bhg0 + k0, &Bhb[buf][w * 32][0]);
    gl16(bhg1 + k0, &Bhb[buf][w * 32 + 16][0]);
  };

  stage(0, 0);
  const int NK = K / 32;
#pragma unroll
  for (int ks = 0; ks < NK; ks++) {
    const int buf = ks & 1;
    __syncthreads();  // drains this wave's stage(buf) + orders prev compute
    if (ks + 1 < NK) stage(buf ^ 1, (ks + 1) * 32);

    short8 fa[4], fbh[4];
#pragma unroll
    for (int r = 0; r < 4; r++)
      fa[r] = *(const short8*)(&Asb[buf][wr + r * 16 + fr][fq * 8]);
#pragma unroll
    for (int c = 0; c < 4; c++)
      fbh[c] = *(const short8*)(&Bhb[buf][wc + c * 16 + fr][fq * 8]);
#pragma unroll
    for (int r = 0; r < 4; r++)
#pragma unroll
      for (int c = 0; c < 4; c++)
        acc[r][c] = __builtin_amdgcn_mfma_f32_16x16x32_bf16(fa[r], fbh[c], acc[r][c], 0, 0, 0);
  }

  // ---- C write (fp8 e4m3; L2 absorbs the 1B scatter)
#pragma unroll
  for (int r = 0; r < 4; r++)
#pragma unroll
    for (int c = 0; c < 4; c++) {
      int colg = col0 + wc + c * 16 + fr;
#pragma unroll
      for (int reg = 0; reg < 4; reg++) {
        int gr = row0 + wr + r * 16 + fq * 4 + reg;
        if (gr < Nrows)
          hout[(size_t)gr * 256 + colg] = f2fp8(acc[r][c][reg]);
      }
    }

  // ---- attention scores: wave's 64 cols = one head (wc 64-aligned)
  const int head = (col0 + wc) >> 6;
  float asv[4], adv[4];
#pragma unroll
  for (int c = 0; c < 4; c++) {
    asv[c] = att_s[col0 + wc + c * 16 + fr];
    adv[c] = att_d[col0 + wc + c * 16 + fr];
  }
#pragma unroll
  for (int r = 0; r < 4; r++)
#pragma unroll
    for (int reg = 0; reg < 4; reg++) {
      float ps = 0.f, pd = 0.f;
#pragma unroll
      for (int c = 0; c < 4; c++) {
        ps += acc[r][c][reg] * asv[c];
        pd += acc[r][c][reg] * adv[c];
      }
      ps += __shfl_xor(ps, 1); pd += __shfl_xor(pd, 1);
      ps += __shfl_xor(ps, 2); pd += __shfl_xor(pd, 2);
      ps += __shfl_xor(ps, 4); pd += __shfl_xor(pd, 4);
      ps += __shfl_xor(ps, 8); pd += __shfl_xor(pd, 8);
      if (fr == 0) {
        int gr = row0 + wr + r * 16 + fq * 4 + reg;
        if (gr < Nrows) {
          a_s[(size_t)gr * 4 + head] = ps;
          a_d[(size_t)gr * 4 + head] = pd;
        }
      }
    }
}

__global__ __launch_bounds__(256)
void k_gemm1(const ushort* __restrict__ xb, const ushort* __restrict__ Bt,
             unsigned char* __restrict__ hout, int Nrows,
             const float* __restrict__ att_s, const float* __restrict__ att_d,
             float* __restrict__ a_s, float* __restrict__ a_d) {
  gemm_body<128>(blockIdx.x, xb, Bt, hout, Nrows, att_s, att_d, a_s, a_d);
}

__global__ __launch_bounds__(256)
void k_gemm2(const ushort* __restrict__ Ah, const ushort* __restrict__ Bt,
             unsigned char* __restrict__ hout, int Nrows,
             const float* __restrict__ att_s, const float* __restrict__ att_d,
             float* __restrict__ a_s, float* __restrict__ a_d) {
  gemm_body<256>(blockIdx.x, Ah, Bt, hout, Nrows, att_s, att_d, a_s, a_d);
}

// ----------------------------- aggregation ---------------------------------
// ONE wave per node; lane owns channels [4*lane, 4*lane+3], head = lane>>4.
// h is FP8 e4m3 for BOTH layers: 4 B/lane gather (256 B/edge), HW cvt decode.
// Padded adjacency: deg = min(cnt[node],64); col2[node<<6 + j] = src*256.
// acc in 2x f32x2 (v_pk_fma_f32). Edge loop unrolled 8/4/1.
// LAYER 1: relu(acc/den + bias) -> plain bf16.
// LAYER 2: fused finale — head-mean + bias + relu + softmax(64) -> outp.
template <int LAYER>
__global__ __launch_bounds__(256)
void k_aggr(const unsigned char* __restrict__ hsrc,
            const int* __restrict__ cnt, const int* __restrict__ col2,
            const float* __restrict__ a_s, const float* __restrict__ a_d,
            const float* __restrict__ bias,
            ushort* __restrict__ out_h, float* __restrict__ outp, int N) {
  __shared__ int   s_sh[4][64];
  __shared__ float w_sh[4][256];
  const int wv = threadIdx.x >> 6;
  const int lane = threadIdx.x & 63;
  const int node = blockIdx.x * 4 + wv;
  if (node >= N) return;
  const int hd = lane >> 4;
  const int deg = min(cnt[node], 64);
  const int beg = node << 6;
  const float4 adst = *(const float4*)(a_d + (size_t)node * 4);

  f32x2 accA = {0.f, 0.f};   // channels lane*4+0, +1
  f32x2 accB = {0.f, 0.f};   // channels lane*4+2, +3
  float wsum = 0.f;
  const char* hbase = (const char*)hsrc + lane * 4;  // 256 B row stride

  {
    int nc = deg;              // deg <= 64: exactly one 64-wide pass
    int off = 0;
    float4 w4 = make_float4(0.f, 0.f, 0.f, 0.f);
    if (lane < nc) {
      off = col2[beg + lane];  // src*256
      const float4 a = *(const float4*)((const char*)a_s + (size_t)((uint)off >> 4));
      float e0 = a.x + adst.x; e0 = e0 > 0.f ? e0 : 0.2f * e0;
      float e1 = a.y + adst.y; e1 = e1 > 0.f ? e1 : 0.2f * e1;
      float e2 = a.z + adst.z; e2 = e2 > 0.f ? e2 : 0.2f * e2;
      float e3 = a.w + adst.w; e3 = e3 > 0.f ? e3 : 0.2f * e3;
      w4 = make_float4(__expf(e0), __expf(e1), __expf(e2), __expf(e3));
    }
    s_sh[wv][lane] = off;
    *(float4*)(&w_sh[wv][lane * 4]) = w4;
    asm volatile("s_waitcnt lgkmcnt(0)" ::: "memory");

    const float* wrow = &w_sh[wv][hd];
    const int*   srow = &s_sh[wv][0];
    int j = 0;
    for (; j + 8 <= nc; j += 8) {
      int o0 = srow[j],     o1 = srow[j + 1], o2 = srow[j + 2], o3 = srow[j + 3];
      int o4 = srow[j + 4], o5 = srow[j + 5], o6 = srow[j + 6], o7 = srow[j + 7];
      float ww0 = wrow[4 * j],      ww1 = wrow[4 * j + 4];
      float ww2 = wrow[4 * j + 8],  ww3 = wrow[4 * j + 12];
      float ww4 = wrow[4 * j + 16], ww5 = wrow[4 * j + 20];
      float ww6 = wrow[4 * j + 24], ww7 = wrow[4 * j + 28];
      uint p0 = *(const uint*)(hbase + (size_t)(uint)o0);
      uint p1 = *(const uint*)(hbase + (size_t)(uint)o1);
      uint p2 = *(const uint*)(hbase + (size_t)(uint)o2);
      uint p3 = *(const uint*)(hbase + (size_t)(uint)o3);
      uint p4 = *(const uint*)(hbase + (size_t)(uint)o4);
      uint p5 = *(const uint*)(hbase + (size_t)(uint)o5);
      uint p6 = *(const uint*)(hbase + (size_t)(uint)o6);
      uint p7 = *(const uint*)(hbase + (size_t)(uint)o7);
      wsum += ww0 + ww1 + ww2 + ww3;
      wsum += ww4 + ww5 + ww6 + ww7;
      f32x2 W;
#define EDGE_FMA(ww, p)                                                     \
      {                                                                     \
        f32x2 lo = __builtin_amdgcn_cvt_pk_f32_fp8((p), false);             \
        f32x2 hi = __builtin_amdgcn_cvt_pk_f32_fp8((p), true);              \
        W.x = (ww); W.y = (ww);                                             \
        accA = __builtin_elementwise_fma(W, lo, accA);                      \
        accB = __builtin_elementwise_fma(W, hi, accB);                      \
      }
      EDGE_FMA(ww0, p0) EDGE_FMA(ww1, p1) EDGE_FMA(ww2, p2) EDGE_FMA(ww3, p3)
      EDGE_FMA(ww4, p4) EDGE_FMA(ww5, p5) EDGE_FMA(ww6, p6) EDGE_FMA(ww7, p7)
    }
    for (; j + 4 <= nc; j += 4) {
      int o0 = srow[j], o1 = srow[j + 1], o2 = srow[j + 2], o3 = srow[j + 3];
      float ww0 = wrow[4 * j],     ww1 = wrow[4 * j + 4];
      float ww2 = wrow[4 * j + 8], ww3 = wrow[4 * j + 12];
      uint p0 = *(const uint*)(hbase + (size_t)(uint)o0);
      uint p1 = *(const uint*)(hbase + (size_t)(uint)o1);
      uint p2 = *(const uint*)(hbase + (size_t)(uint)o2);
      uint p3 = *(const uint*)(hbase + (size_t)(uint)o3);
      wsum += ww0 + ww1 + ww2 + ww3;
      f32x2 W;
      EDGE_FMA(ww0, p0) EDGE_FMA(ww1, p1) EDGE_FMA(ww2, p2) EDGE_FMA(ww3, p3)
    }
    for (; j < nc; j++) {
      int o = srow[j];
      float ww = wrow[4 * j];
      uint p = *(const uint*)(hbase + (size_t)(uint)o);
      wsum += ww;
      f32x2 W;
      EDGE_FMA(ww, p)
    }
#undef EDGE_FMA
  }

  float inv = 1.0f / wsum;  // deg>=1 via self-loop
  float4 v = make_float4(accA.x * inv, accA.y * inv, accB.x * inv, accB.y * inv);

  if (LAYER == 1) {
    const float4 bv = *(const float4*)(bias + lane * 4);
    v.x = fmaxf(v.x + bv.x, 0.f);
    v.y = fmaxf(v.y + bv.y, 0.f);
    v.z = fmaxf(v.z + bv.z, 0.f);
    v.w = fmaxf(v.w + bv.w, 0.f);
    ushort4 h;
    h.x = f2bf(v.x); h.y = f2bf(v.y); h.z = f2bf(v.z); h.w = f2bf(v.w);
    *(ushort4*)(out_h + (size_t)node * 256 + lane * 4) = h;
  } else {
    // fused finale: head-mean + bias + relu + softmax(64)
    v.x += __shfl_xor(v.x, 16); v.y += __shfl_xor(v.y, 16);
    v.z += __shfl_xor(v.z, 16); v.w += __shfl_xor(v.w, 16);
    v.x += __shfl_xor(v.x, 32); v.y += __shfl_xor(v.y, 32);
    v.z += __shfl_xor(v.z, 32); v.w += __shfl_xor(v.w, 32);
    const int c4 = (lane & 15) * 4;
    const float4 bv = *(const float4*)(bias + c4);
    v.x = fmaxf(v.x * 0.25f + bv.x, 0.f);
    v.y = fmaxf(v.y * 0.25f + bv.y, 0.f);
    v.z = fmaxf(v.z * 0.25f + bv.z, 0.f);
    v.w = fmaxf(v.w * 0.25f + bv.w, 0.f);
    float mx = fmaxf(fmaxf(v.x, v.y), fmaxf(v.z, v.w));
    for (int off = 8; off >= 1; off >>= 1) mx = fmaxf(mx, __shfl_xor(mx, off));
    v.x = __expf(v.x - mx); v.y = __expf(v.y - mx);
    v.z = __expf(v.z - mx); v.w = __expf(v.w - mx);
    float sum = v.x + v.y + v.z + v.w;
    for (int off = 8; off >= 1; off >>= 1) sum += __shfl_xor(sum, off);
    float is = 1.0f / sum;
    v.x *= is; v.y *= is; v.z *= is; v.w *= is;
    if (lane < 16) *(float4*)(outp + (size_t)node * 64 + c4) = v;
  }
}

// ---------------------------------------------------------------------------

extern "C" void kernel_launch(void* const* d_in, const int* in_sizes, int n_in,
                              void* d_out, int out_size, void* d_ws, size_t ws_size,
                              hipStream_t stream) {
  const float* x   = (const float*)d_in[0];
  const int*   ei  = (const int*)d_in[1];
  const float* W1  = (const float*)d_in[2];
  const float* as1 = (const float*)d_in[3];
  const float* ad1 = (const float*)d_in[4];
  const float* b1  = (const float*)d_in[5];
  const float* W2  = (const float*)d_in[6];
  const float* as2 = (const float*)d_in[7];
  const float* ad2 = (const float*)d_in[8];
  const float* b2  = (const float*)d_in[9];
  float* out = (float*)d_out;

  const int N = in_sizes[0] / 128;
  const int E = in_sizes[1] / 2;
  const int* srcv = ei;
  const int* dstv = ei + E;

  // ---- workspace layout
  unsigned char* h8 = (unsigned char*)d_ws;       // [N,256] fp8 (both layers)
  ushort* hb   = (ushort*)(h8 + (size_t)N * 256); // [N,256] bf16 (aggr1 out)
  ushort* w1t  = hb + (size_t)N * 256;            // [256][128] bf16
  ushort* w2t  = w1t + 256 * 128;                 // [256][256] bf16
  float*  zbuf = (float*)(w2t + 256 * 256);       // a_s1,a_d1,a_s2,a_d2 [16N]
  float* a_s1 = zbuf;
  float* a_d1 = a_s1 + (size_t)N * 4;
  float* a_s2 = a_d1 + (size_t)N * 4;
  float* a_d2 = a_s2 + (size_t)N * 4;
  int* cnt    = (int*)(zbuf + (size_t)N * 16);    // [N]  (memset region)
  int* col2   = cnt + N;                          // [N*64] padded adjacency
  ushort* xb  = (ushort*)(col2 + (size_t)N * 64); // [N,128] bf16 of x

  const int eb8 = (E + 2047) / 2048;  // 8 edges/thread hist blocks
  const int ng = N * 16;              // x-conversion groups (8 elems each)
  const int xcb = (ng + 255) / 256;   // x-conversion blocks

  // XCD-aligned swizzled 1-D grid: 16 blocks per group of 8 row blocks
  const int nrb = (N + 127) / 128;
  const int gemm_blocks = ((nrb + 7) / 8) * 16;
  const int wb = (N + 3) / 4;  // one wave per node

  hipMemsetAsync(cnt, 0, (size_t)N * 4, stream);
  k_prep_hist<<<eb8 + 384 + xcb, 256, 0, stream>>>(
      W1, W2, w1t, w2t, x, xb, srcv, dstv, cnt, col2, E, ng, eb8);
  k_gemm1<<<gemm_blocks, 256, 0, stream>>>(xb, w1t, h8, N,
                                           as1, ad1, a_s1, a_d1);
  k_aggr<1><<<wb, 256, 0, stream>>>(h8, cnt, col2, a_s1, a_d1, b1,
                                    hb, nullptr, N);
  k_gemm2<<<gemm_blocks, 256, 0, stream>>>(hb, w2t, h8, N,
                                           as2, ad2, a_s2, a_d2);
  k_aggr<2><<<wb, 256, 0, stream>>>(h8, cnt, col2, a_s2, a_d2, b2,
                                    nullptr, out, N);
}

// Round 13
// 253.065 us; speedup vs baseline: 1.0658x; 1.0658x over previous
//
#include <hip/hip_runtime.h>

// ---------------------------------------------------------------------------
// 2-layer GAT (PyG GATConv), MI355X.
// R34 (post-mortem of R33 = 269.7us regression; R32 = 249.7us best):
//   R33 lessons: (a) un-fusing hist from gemm1 re-exposed gemm1 + memset on
//   the serial path (+20us) -> R32's fused schedule restored; (b) the
//   decisive datum: hist occupancy 21% (391 blocks = 1.5/CU) for a pure
//   atomic-latency workload (~900cy RTT, VALU 1.5%) -> UNDER-PARALLELIZED.
//   Change (single variable vs R32): hist 8 -> 2 edges/thread
//   (391 -> 1563 blocks). Keeps R30's two-phase structure (phase separation
//   was the win); block count now provides the latency-hiding concurrency.
//   Tiny hist blocks (0 LDS) backfill every CU's spare wave slots behind
//   the 5-blocks/CU LDS-capped gemm.
//   Everything else byte-frozen from R32.
// ---------------------------------------------------------------------------

typedef __attribute__((ext_vector_type(8))) short short8;
typedef __attribute__((ext_vector_type(4))) float f32x4;
typedef __attribute__((ext_vector_type(2))) float f32x2;

static __device__ __forceinline__ ushort f2bf(float f) {  // RNE
  uint u = __float_as_uint(f);
  return (ushort)((u + 0x7FFFu + ((u >> 16) & 1u)) >> 16);
}
static __device__ __forceinline__ float bf2f(ushort s) {
  return __uint_as_float(((uint)s) << 16);
}
static __device__ __forceinline__ unsigned char f2fp8(float f) {  // e4m3 (HW)
  int p = __builtin_amdgcn_cvt_pk_fp8_f32(f, f, 0, false);
  return (unsigned char)(p & 0xFF);
}
static __device__ __forceinline__ uint4 cvt8bf(const float4& a, const float4& b) {
  uint4 hh;
  hh.x = (uint)f2bf(a.x) | ((uint)f2bf(a.y) << 16);
  hh.y = (uint)f2bf(a.z) | ((uint)f2bf(a.w) << 16);
  hh.z = (uint)f2bf(b.x) | ((uint)f2bf(b.y) << 16);
  hh.w = (uint)f2bf(b.z) | ((uint)f2bf(b.w) << 16);
  return hh;
}
// async global->LDS, 16B per lane (wave-uniform LDS base + lane*16)
static __device__ __forceinline__ void gl16(const ushort* g, ushort* l) {
  __builtin_amdgcn_global_load_lds(
      (const __attribute__((address_space(1))) uint*)(g),
      (__attribute__((address_space(3))) uint*)(l), 16, 0, 0);
}

// -------- weight-prep (plain bf16) + x->bf16 + cnt zeroing -----------------
__global__ __launch_bounds__(256)
void k_prep(const float* __restrict__ W1, const float* __restrict__ W2,
            ushort* __restrict__ w1t, ushort* __restrict__ w2t,
            const float* __restrict__ x, ushort* __restrict__ xb,
            int* __restrict__ cnt, int N,
            int ng /* = N*16 groups of 8 elems */, int xcb) {
  const int b = blockIdx.x;
  if (b < 128) {  // W1 [128][256] -> [256][128] bf16
    int gid = b * 256 + threadIdx.x;
    int c = gid & 255, k = gid >> 8;
    w1t[(size_t)c * 128 + k] = f2bf(W1[(size_t)k * 256 + c]);
  } else if (b < 384) {  // W2 [256][256] -> [256][256] bf16
    int gid = (b - 128) * 256 + threadIdx.x;
    int c = gid & 255, k = gid >> 8;
    w2t[(size_t)c * 256 + k] = f2bf(W2[(size_t)k * 256 + c]);
  } else if (b < 384 + xcb) {  // x fp32 -> bf16 (RNE), 8 elems/thread
    int i = (b - 384) * 256 + threadIdx.x;
    if (i < ng) {
      const float4* xp = (const float4*)x + (size_t)i * 2;
      float4 a = xp[0], bb = xp[1];
      ((uint4*)xb)[i] = cvt8bf(a, bb);
    }
  } else {  // zero cnt, 4 ints/thread
    int i = (b - 384 - xcb) * 1024 + threadIdx.x;
#pragma unroll
    for (int k = 0; k < 4; k++) {
      int j = i + k * 256;
      if (j < N) cnt[j] = 0;
    }
  }
}

// ----------------------------- MFMA GEMM body ------------------------------
// 256 threads / 4 waves; block tile 128 rows x 128 cols (col-half of C).
// Wave tile 64x64: wr=(w>>1)*64, wc=(w&1)*64; acc[4][4].
// Async-staged double-buffered LDS via global_load_lds; one __syncthreads
// per K-step; next stage issued right after the barrier. Single-term
// (plain bf16 W): A + B tiles only, LDS 32KB -> 5 blocks/CU.
// C[N,256] = A_bf16 @ B[K,256], Bt stored [256][K]. C -> FP8 e4m3.
// XCD-aligned swizzle: col-halves of a row block differ by 8 block ids.
template <int K>
static __device__ __forceinline__
void gemm_body(int bid, const ushort* __restrict__ Ah,
               const ushort* __restrict__ Bt,
               unsigned char* __restrict__ hout, int Nrows,
               const float* __restrict__ att_s, const float* __restrict__ att_d,
               float* __restrict__ a_s, float* __restrict__ a_d) {
  __shared__ ushort Asb[2][128][32];
  __shared__ ushort Bhb[2][128][32];

  const int nrb = (Nrows + 127) >> 7;
  const int rb = (bid >> 4) * 8 + (bid & 7);
  const int ch = (bid >> 3) & 1;
  if (rb >= nrb) return;
  const int row0 = rb * 128;
  const int col0 = ch * 128;

  const int t = threadIdx.x;
  const int lane = t & 63;
  const int w = t >> 6;            // 0..3
  const int wr = (w >> 1) * 64;
  const int wc = (w & 1) * 64;
  const int fr = lane & 15;
  const int fq = lane >> 4;

  // staging source addresses (per-lane)
  const int srow = lane >> 2;          // 0..15
  const int skc = (lane & 3) * 8;      // k offset in elems
  int ar0 = row0 + w * 32 + srow;
  int ar1 = ar0 + 16;
  ar0 = ar0 < Nrows ? ar0 : Nrows - 1;  // clamped tail (stores guarded later)
  ar1 = ar1 < Nrows ? ar1 : Nrows - 1;
  const ushort* agp0 = Ah + (size_t)ar0 * K + skc;
  const ushort* agp1 = Ah + (size_t)ar1 * K + skc;
  const ushort* bhg0 = Bt + (size_t)(col0 + w * 32 + srow) * K + skc;
  const ushort* bhg1 = bhg0 + (size_t)16 * K;

  f32x4 acc[4][4] = {};

  auto stage = [&](int buf, int k0) {
    gl16(agp0 + k0, &Asb[buf][w * 32][0]);
    gl16(agp1 + k0, &Asb[buf][w * 32 + 16][0]);
    gl16(bhg0 + k0, &Bhb[buf][w * 32][0]);
    gl16(bhg1 + k0, &Bhb[buf][w * 32 + 16][0]);
  };

  stage(0, 0);
  const int NK = K / 32;
#pragma unroll
  for (int ks = 0; ks < NK; ks++) {
    const int buf = ks & 1;
    __syncthreads();  // drains this wave's stage(buf) + orders prev compute
    if (ks + 1 < NK) stage(buf ^ 1, (ks + 1) * 32);

    short8 fa[4], fbh[4];
#pragma unroll
    for (int r = 0; r < 4; r++)
      fa[r] = *(const short8*)(&Asb[buf][wr + r * 16 + fr][fq * 8]);
#pragma unroll
    for (int c = 0; c < 4; c++)
      fbh[c] = *(const short8*)(&Bhb[buf][wc + c * 16 + fr][fq * 8]);
#pragma unroll
    for (int r = 0; r < 4; r++)
#pragma unroll
      for (int c = 0; c < 4; c++)
        acc[r][c] = __builtin_amdgcn_mfma_f32_16x16x32_bf16(fa[r], fbh[c], acc[r][c], 0, 0, 0);
  }

  // ---- C write (fp8 e4m3; L2 absorbs the 1B scatter)
#pragma unroll
  for (int r = 0; r < 4; r++)
#pragma unroll
    for (int c = 0; c < 4; c++) {
      int colg = col0 + wc + c * 16 + fr;
#pragma unroll
      for (int reg = 0; reg < 4; reg++) {
        int gr = row0 + wr + r * 16 + fq * 4 + reg;
        if (gr < Nrows)
          hout[(size_t)gr * 256 + colg] = f2fp8(acc[r][c][reg]);
      }
    }

  // ---- attention scores: wave's 64 cols = one head (wc 64-aligned)
  const int head = (col0 + wc) >> 6;
  float asv[4], adv[4];
#pragma unroll
  for (int c = 0; c < 4; c++) {
    asv[c] = att_s[col0 + wc + c * 16 + fr];
    adv[c] = att_d[col0 + wc + c * 16 + fr];
  }
#pragma unroll
  for (int r = 0; r < 4; r++)
#pragma unroll
    for (int reg = 0; reg < 4; reg++) {
      float ps = 0.f, pd = 0.f;
#pragma unroll
      for (int c = 0; c < 4; c++) {
        ps += acc[r][c][reg] * asv[c];
        pd += acc[r][c][reg] * adv[c];
      }
      ps += __shfl_xor(ps, 1); pd += __shfl_xor(pd, 1);
      ps += __shfl_xor(ps, 2); pd += __shfl_xor(pd, 2);
      ps += __shfl_xor(ps, 4); pd += __shfl_xor(pd, 4);
      ps += __shfl_xor(ps, 8); pd += __shfl_xor(pd, 8);
      if (fr == 0) {
        int gr = row0 + wr + r * 16 + fq * 4 + reg;
        if (gr < Nrows) {
          a_s[(size_t)gr * 4 + head] = ps;
          a_d[(size_t)gr * 4 + head] = pd;
        }
      }
    }
}

// ---- fused: gemm1 blocks first, TWO-PHASE padded-adj hist backfill --------
// Hist: 2 edges/thread (512/block, 1563 blocks) for CONCURRENCY: the pure
// atomic-latency phase needs resident waves, not per-thread depth (R33:
// occ 21% at 8/thread). Phase A: coalesced dst/src loads. Phase B: 2
// atomicAdds. Phase C: 2 scattered col2 stores.
__global__ __launch_bounds__(256)
void k_gemm1_hist(const ushort* __restrict__ xb,
                  const ushort* __restrict__ Bt,
                  unsigned char* __restrict__ hout, int Nrows,
                  const float* __restrict__ att_s,
                  const float* __restrict__ att_d,
                  float* __restrict__ a_s, float* __restrict__ a_d,
                  const int* __restrict__ srcv, const int* __restrict__ dstv,
                  int* __restrict__ cnt, int* __restrict__ col2,
                  int E, int gemm_blocks) {
  if ((int)blockIdx.x < gemm_blocks) {
    gemm_body<128>(blockIdx.x, xb, Bt, hout, Nrows,
                   att_s, att_d, a_s, a_d);
  } else {
    int base = ((int)blockIdx.x - gemm_blocks) * 512 + threadIdx.x;
    int d[2], v[2], s[2];
#pragma unroll
    for (int k = 0; k < 2; k++) {
      int i = base + k * 256;
      bool ok = i < E;
      d[k] = ok ? dstv[i] : 0;
      v[k] = ok ? (srcv[i] << 8) : 0;
    }
#pragma unroll
    for (int k = 0; k < 2; k++) {
      int i = base + k * 256;
      s[k] = (i < E) ? atomicAdd(&cnt[d[k]], 1) : 64;
    }
#pragma unroll
    for (int k = 0; k < 2; k++) {
      int i = base + k * 256;
      if (i < E && s[k] < 64) col2[(d[k] << 6) + s[k]] = v[k];
    }
  }
}

__global__ __launch_bounds__(256)
void k_gemm2(const ushort* __restrict__ Ah,
             const ushort* __restrict__ Bt,
             unsigned char* __restrict__ hout, int Nrows,
             const float* __restrict__ att_s, const float* __restrict__ att_d,
             float* __restrict__ a_s, float* __restrict__ a_d) {
  gemm_body<256>(blockIdx.x, Ah, Bt, hout, Nrows,
                 att_s, att_d, a_s, a_d);
}

// ----------------------------- aggregation ---------------------------------
// ONE wave per node; lane owns channels [4*lane, 4*lane+3], head = lane>>4.
// h is FP8 e4m3 for BOTH layers: 4 B/lane gather (256 B/edge), HW cvt decode.
// Padded adjacency: deg = min(cnt[node],64); col2[node<<6 + j] = src*256.
// acc in 2x f32x2 (v_pk_fma_f32). Edge loop unrolled 8/4/1.
// LAYER 1: relu(acc/den + bias) -> plain bf16.
// LAYER 2: fused finale — head-mean + bias + relu + softmax(64) -> outp.
template <int LAYER>
__global__ __launch_bounds__(256)
void k_aggr(const unsigned char* __restrict__ hsrc,
            const int* __restrict__ cnt, const int* __restrict__ col2,
            const float* __restrict__ a_s, const float* __restrict__ a_d,
            const float* __restrict__ bias,
            ushort* __restrict__ out_h, float* __restrict__ outp, int N) {
  __shared__ int   s_sh[4][64];
  __shared__ float w_sh[4][256];
  const int wv = threadIdx.x >> 6;
  const int lane = threadIdx.x & 63;
  const int node = blockIdx.x * 4 + wv;
  if (node >= N) return;
  const int hd = lane >> 4;
  const int deg = min(cnt[node], 64);
  const int beg = node << 6;
  const float4 adst = *(const float4*)(a_d + (size_t)node * 4);

  f32x2 accA = {0.f, 0.f};   // channels lane*4+0, +1
  f32x2 accB = {0.f, 0.f};   // channels lane*4+2, +3
  float wsum = 0.f;
  const char* hbase = (const char*)hsrc + lane * 4;  // 256 B row stride

  {
    int nc = deg;              // deg <= 64: exactly one 64-wide pass
    int off = 0;
    float4 w4 = make_float4(0.f, 0.f, 0.f, 0.f);
    if (lane < nc) {
      off = col2[beg + lane];  // src*256
      const float4 a = *(const float4*)((const char*)a_s + (size_t)((uint)off >> 4));
      float e0 = a.x + adst.x; e0 = e0 > 0.f ? e0 : 0.2f * e0;
      float e1 = a.y + adst.y; e1 = e1 > 0.f ? e1 : 0.2f * e1;
      float e2 = a.z + adst.z; e2 = e2 > 0.f ? e2 : 0.2f * e2;
      float e3 = a.w + adst.w; e3 = e3 > 0.f ? e3 : 0.2f * e3;
      w4 = make_float4(__expf(e0), __expf(e1), __expf(e2), __expf(e3));
    }
    s_sh[wv][lane] = off;
    *(float4*)(&w_sh[wv][lane * 4]) = w4;
    asm volatile("s_waitcnt lgkmcnt(0)" ::: "memory");

    const float* wrow = &w_sh[wv][hd];
    const int*   srow = &s_sh[wv][0];
    int j = 0;
    for (; j + 8 <= nc; j += 8) {
      int o0 = srow[j],     o1 = srow[j + 1], o2 = srow[j + 2], o3 = srow[j + 3];
      int o4 = srow[j + 4], o5 = srow[j + 5], o6 = srow[j + 6], o7 = srow[j + 7];
      float ww0 = wrow[4 * j],      ww1 = wrow[4 * j + 4];
      float ww2 = wrow[4 * j + 8],  ww3 = wrow[4 * j + 12];
      float ww4 = wrow[4 * j + 16], ww5 = wrow[4 * j + 20];
      float ww6 = wrow[4 * j + 24], ww7 = wrow[4 * j + 28];
      uint p0 = *(const uint*)(hbase + (size_t)(uint)o0);
      uint p1 = *(const uint*)(hbase + (size_t)(uint)o1);
      uint p2 = *(const uint*)(hbase + (size_t)(uint)o2);
      uint p3 = *(const uint*)(hbase + (size_t)(uint)o3);
      uint p4 = *(const uint*)(hbase + (size_t)(uint)o4);
      uint p5 = *(const uint*)(hbase + (size_t)(uint)o5);
      uint p6 = *(const uint*)(hbase + (size_t)(uint)o6);
      uint p7 = *(const uint*)(hbase + (size_t)(uint)o7);
      wsum += ww0 + ww1 + ww2 + ww3;
      wsum += ww4 + ww5 + ww6 + ww7;
      f32x2 W;
#define EDGE_FMA(ww, p)                                                     \
      {                                                                     \
        f32x2 lo = __builtin_amdgcn_cvt_pk_f32_fp8((p), false);             \
        f32x2 hi = __builtin_amdgcn_cvt_pk_f32_fp8((p), true);              \
        W.x = (ww); W.y = (ww);                                             \
        accA = __builtin_elementwise_fma(W, lo, accA);                      \
        accB = __builtin_elementwise_fma(W, hi, accB);                      \
      }
      EDGE_FMA(ww0, p0) EDGE_FMA(ww1, p1) EDGE_FMA(ww2, p2) EDGE_FMA(ww3, p3)
      EDGE_FMA(ww4, p4) EDGE_FMA(ww5, p5) EDGE_FMA(ww6, p6) EDGE_FMA(ww7, p7)
    }
    for (; j + 4 <= nc; j += 4) {
      int o0 = srow[j], o1 = srow[j + 1], o2 = srow[j + 2], o3 = srow[j + 3];
      float ww0 = wrow[4 * j],     ww1 = wrow[4 * j + 4];
      float ww2 = wrow[4 * j + 8], ww3 = wrow[4 * j + 12];
      uint p0 = *(const uint*)(hbase + (size_t)(uint)o0);
      uint p1 = *(const uint*)(hbase + (size_t)(uint)o1);
      uint p2 = *(const uint*)(hbase + (size_t)(uint)o2);
      uint p3 = *(const uint*)(hbase + (size_t)(uint)o3);
      wsum += ww0 + ww1 + ww2 + ww3;
      f32x2 W;
      EDGE_FMA(ww0, p0) EDGE_FMA(ww1, p1) EDGE_FMA(ww2, p2) EDGE_FMA(ww3, p3)
    }
    for (; j < nc; j++) {
      int o = srow[j];
      float ww = wrow[4 * j];
      uint p = *(const uint*)(hbase + (size_t)(uint)o);
      wsum += ww;
      f32x2 W;
      EDGE_FMA(ww, p)
    }
#undef EDGE_FMA
  }

  float inv = 1.0f / wsum;  // deg>=1 via self-loop
  float4 v = make_float4(accA.x * inv, accA.y * inv, accB.x * inv, accB.y * inv);

  if (LAYER == 1) {
    const float4 bv = *(const float4*)(bias + lane * 4);
    v.x = fmaxf(v.x + bv.x, 0.f);
    v.y = fmaxf(v.y + bv.y, 0.f);
    v.z = fmaxf(v.z + bv.z, 0.f);
    v.w = fmaxf(v.w + bv.w, 0.f);
    ushort4 h;
    h.x = f2bf(v.x); h.y = f2bf(v.y); h.z = f2bf(v.z); h.w = f2bf(v.w);
    *(ushort4*)(out_h + (size_t)node * 256 + lane * 4) = h;
  } else {
    // fused finale: head-mean + bias + relu + softmax(64)
    v.x += __shfl_xor(v.x, 16); v.y += __shfl_xor(v.y, 16);
    v.z += __shfl_xor(v.z, 16); v.w += __shfl_xor(v.w, 16);
    v.x += __shfl_xor(v.x, 32); v.y += __shfl_xor(v.y, 32);
    v.z += __shfl_xor(v.z, 32); v.w += __shfl_xor(v.w, 32);
    const int c4 = (lane & 15) * 4;
    const float4 bv = *(const float4*)(bias + c4);
    v.x = fmaxf(v.x * 0.25f + bv.x, 0.f);
    v.y = fmaxf(v.y * 0.25f + bv.y, 0.f);
    v.z = fmaxf(v.z * 0.25f + bv.z, 0.f);
    v.w = fmaxf(v.w * 0.25f + bv.w, 0.f);
    float mx = fmaxf(fmaxf(v.x, v.y), fmaxf(v.z, v.w));
    for (int off = 8; off >= 1; off >>= 1) mx = fmaxf(mx, __shfl_xor(mx, off));
    v.x = __expf(v.x - mx); v.y = __expf(v.y - mx);
    v.z = __expf(v.z - mx); v.w = __expf(v.w - mx);
    float sum = v.x + v.y + v.z + v.w;
    for (int off = 8; off >= 1; off >>= 1) sum += __shfl_xor(sum, off);
    float is = 1.0f / sum;
    v.x *= is; v.y *= is; v.z *= is; v.w *= is;
    if (lane < 16) *(float4*)(outp + (size_t)node * 64 + c4) = v;
  }
}

// ---------------------------------------------------------------------------

extern "C" void kernel_launch(void* const* d_in, const int* in_sizes, int n_in,
                              void* d_out, int out_size, void* d_ws, size_t ws_size,
                              hipStream_t stream) {
  const float* x   = (const float*)d_in[0];
  const int*   ei  = (const int*)d_in[1];
  const float* W1  = (const float*)d_in[2];
  const float* as1 = (const float*)d_in[3];
  const float* ad1 = (const float*)d_in[4];
  const float* b1  = (const float*)d_in[5];
  const float* W2  = (const float*)d_in[6];
  const float* as2 = (const float*)d_in[7];
  const float* ad2 = (const float*)d_in[8];
  const float* b2  = (const float*)d_in[9];
  float* out = (float*)d_out;

  const int N = in_sizes[0] / 128;
  const int E = in_sizes[1] / 2;
  const int* srcv = ei;
  const int* dstv = ei + E;

  // ---- workspace layout
  unsigned char* h8 = (unsigned char*)d_ws;       // [N,256] fp8 (both layers)
  ushort* hb   = (ushort*)(h8 + (size_t)N * 256); // [N,256] bf16 (aggr1 out)
  ushort* w1t  = hb + (size_t)N * 256;            // [256][128] bf16
  ushort* w2t  = w1t + 256 * 128;                 // [256][256] bf16
  float*  zbuf = (float*)(w2t + 256 * 256);       // a_s1,a_d1,a_s2,a_d2 [16N]
  float* a_s1 = zbuf;
  float* a_d1 = a_s1 + (size_t)N * 4;
  float* a_s2 = a_d1 + (size_t)N * 4;
  float* a_d2 = a_s2 + (size_t)N * 4;
  int* cnt    = (int*)(zbuf + (size_t)N * 16);    // [N]  (zeroed by k_prep)
  int* col2   = cnt + N;                          // [N*64] padded adjacency
  ushort* xb  = (ushort*)(col2 + (size_t)N * 64); // [N,128] bf16 of x

  const int eb2 = (E + 511) / 512;    // 2 edges/thread hist blocks
  const int ng = N * 16;              // x-conversion groups (8 elems each)
  const int xcb = (ng + 255) / 256;   // x-conversion blocks
  const int zb  = (N + 1023) / 1024;  // cnt zeroing blocks (4 ints/thread)

  // XCD-aligned swizzled 1-D grid: 16 blocks per group of 8 row blocks
  const int nrb = (N + 127) / 128;
  const int gemm_blocks = ((nrb + 7) / 8) * 16;
  const int wb = (N + 3) / 4;  // one wave per node

  k_prep<<<384 + xcb + zb, 256, 0, stream>>>(W1, W2, w1t, w2t,
                                             x, xb, cnt, N, ng, xcb);
  k_gemm1_hist<<<gemm_blocks + eb2, 256, 0, stream>>>(
      xb, w1t, h8, N, as1, ad1, a_s1, a_d1,
      srcv, dstv, cnt, col2, E, gemm_blocks);
  k_aggr<1><<<wb, 256, 0, stream>>>(h8, cnt, col2, a_s1, a_d1, b1,
                                    hb, nullptr, N);
  k_gemm2<<<gemm_blocks, 256, 0, stream>>>(hb, w2t, h8, N,
                                           as2, ad2, a_s2, a_d2);
  k_aggr<2><<<wb, 256, 0, stream>>>(h8, cnt, col2, a_s2, a_d2, b2,
                                    nullptr, out, N);
}

// Round 14
// 252.464 us; speedup vs baseline: 1.0684x; 1.0024x over previous
//
#include <hip/hip_runtime.h>

// ---------------------------------------------------------------------------
// 2-layer GAT (PyG GATConv), MI355X.
// R35 (post-mortem of R34 = 253.1; hist knobs dead, occupancy stuck 18%):
//   RECOMBINE MEASURED-GOOD PIECES. The padded adjacency needs NO scan:
//   col2 address = (dst<<6) + pe[i]. So split R29-R34's expensive in-kernel
//   dependent chain (atomicAdd -> wait -> scattered store) across kernels:
//   (1) k_prep_hist = R26's EXACT structure (W-prep + x-cvt + atomicAdd with
//       COALESCED pe[i] write) -- measured 48.8-51.0us in R26.
//   (2) k_gemm1_scatter = R22's proven pattern: gemm blocks first, scatter
//       backfill (col2[(d<<6)+pe]=src<<8; dst/pe/src all coalesced reads,
//       dependency-free scattered stores) hides behind the 1-term gemm.
//   (3) aggr1 / gemm2 / aggr2 byte-frozen from R32.
//   6 launches: memset, prep_hist, gemm1_scatter, aggr1, gemm2, aggr2.
// ---------------------------------------------------------------------------

typedef __attribute__((ext_vector_type(8))) short short8;
typedef __attribute__((ext_vector_type(4))) float f32x4;
typedef __attribute__((ext_vector_type(2))) float f32x2;

static __device__ __forceinline__ ushort f2bf(float f) {  // RNE
  uint u = __float_as_uint(f);
  return (ushort)((u + 0x7FFFu + ((u >> 16) & 1u)) >> 16);
}
static __device__ __forceinline__ float bf2f(ushort s) {
  return __uint_as_float(((uint)s) << 16);
}
static __device__ __forceinline__ unsigned char f2fp8(float f) {  // e4m3 (HW)
  int p = __builtin_amdgcn_cvt_pk_fp8_f32(f, f, 0, false);
  return (unsigned char)(p & 0xFF);
}
static __device__ __forceinline__ uint4 cvt8bf(const float4& a, const float4& b) {
  uint4 hh;
  hh.x = (uint)f2bf(a.x) | ((uint)f2bf(a.y) << 16);
  hh.y = (uint)f2bf(a.z) | ((uint)f2bf(a.w) << 16);
  hh.z = (uint)f2bf(b.x) | ((uint)f2bf(b.y) << 16);
  hh.w = (uint)f2bf(b.z) | ((uint)f2bf(b.w) << 16);
  return hh;
}
// async global->LDS, 16B per lane (wave-uniform LDS base + lane*16)
static __device__ __forceinline__ void gl16(const ushort* g, ushort* l) {
  __builtin_amdgcn_global_load_lds(
      (const __attribute__((address_space(1))) uint*)(g),
      (__attribute__((address_space(3))) uint*)(l), 16, 0, 0);
}

// ---- R26-structure: weight-prep + dst histogram (coalesced pe) + x->bf16 --
__global__ __launch_bounds__(256)
void k_prep_hist(const float* __restrict__ W1, const float* __restrict__ W2,
                 ushort* __restrict__ w1t, ushort* __restrict__ w2t,
                 const int* __restrict__ dstv, int* __restrict__ cnt,
                 int* __restrict__ pe, int E,
                 const float* __restrict__ x, ushort* __restrict__ xb,
                 int ng) {
  const int b = blockIdx.x;
  const int eb = (E + 255) >> 8;
  if (b < 128) {  // W1 [128][256] -> [256][128] bf16
    int gid = b * 256 + threadIdx.x;
    int c = gid & 255, k = gid >> 8;
    w1t[(size_t)c * 128 + k] = f2bf(W1[(size_t)k * 256 + c]);
  } else if (b < 384) {  // W2 [256][256] -> [256][256] bf16
    int gid = (b - 128) * 256 + threadIdx.x;
    int c = gid & 255, k = gid >> 8;
    w2t[(size_t)c * 256 + k] = f2bf(W2[(size_t)k * 256 + c]);
  } else if (b < 384 + eb) {  // histogram; atomic return = edge's slot (pe)
    int i = (b - 384) * 256 + threadIdx.x;
    if (i < E) pe[i] = atomicAdd(&cnt[dstv[i]], 1);
  } else {  // x fp32 -> bf16 (RNE), 8 elems/thread
    int i = (b - 384 - eb) * 256 + threadIdx.x;
    if (i < ng) {
      const float4* xp = (const float4*)x + (size_t)i * 2;
      float4 a = xp[0], bb = xp[1];
      ((uint4*)xb)[i] = cvt8bf(a, bb);
    }
  }
}

// ----------------------------- MFMA GEMM body ------------------------------
// 256 threads / 4 waves; block tile 128 rows x 128 cols (col-half of C).
// Wave tile 64x64: wr=(w>>1)*64, wc=(w&1)*64; acc[4][4].
// Async-staged double-buffered LDS via global_load_lds; one __syncthreads
// per K-step; next stage issued right after the barrier. Single-term
// (plain bf16 W): A + B tiles only, LDS 32KB -> 5 blocks/CU.
// C[N,256] = A_bf16 @ B[K,256], Bt stored [256][K]. C -> FP8 e4m3.
// XCD-aligned swizzle: col-halves of a row block differ by 8 block ids.
template <int K>
static __device__ __forceinline__
void gemm_body(int bid, const ushort* __restrict__ Ah,
               const ushort* __restrict__ Bt,
               unsigned char* __restrict__ hout, int Nrows,
               const float* __restrict__ att_s, const float* __restrict__ att_d,
               float* __restrict__ a_s, float* __restrict__ a_d) {
  __shared__ ushort Asb[2][128][32];
  __shared__ ushort Bhb[2][128][32];

  const int nrb = (Nrows + 127) >> 7;
  const int rb = (bid >> 4) * 8 + (bid & 7);
  const int ch = (bid >> 3) & 1;
  if (rb >= nrb) return;
  const int row0 = rb * 128;
  const int col0 = ch * 128;

  const int t = threadIdx.x;
  const int lane = t & 63;
  const int w = t >> 6;            // 0..3
  const int wr = (w >> 1) * 64;
  const int wc = (w & 1) * 64;
  const int fr = lane & 15;
  const int fq = lane >> 4;

  // staging source addresses (per-lane)
  const int srow = lane >> 2;          // 0..15
  const int skc = (lane & 3) * 8;      // k offset in elems
  int ar0 = row0 + w * 32 + srow;
  int ar1 = ar0 + 16;
  ar0 = ar0 < Nrows ? ar0 : Nrows - 1;  // clamped tail (stores guarded later)
  ar1 = ar1 < Nrows ? ar1 : Nrows - 1;
  const ushort* agp0 = Ah + (size_t)ar0 * K + skc;
  const ushort* agp1 = Ah + (size_t)ar1 * K + skc;
  const ushort* bhg0 = Bt + (size_t)(col0 + w * 32 + srow) * K + skc;
  const ushort* bhg1 = bhg0 + (size_t)16 * K;

  f32x4 acc[4][4] = {};

  auto stage = [&](int buf, int k0) {
    gl16(agp0 + k0, &Asb[buf][w * 32][0]);
    gl16(agp1 + k0, &Asb[buf][w * 32 + 16][0]);
    gl16(bhg0 + k0, &Bhb[buf][w * 32][0]);
    gl16(bhg1 + k0, &Bhb[buf][w * 32 + 16][0]);
  };

  stage(0, 0);
  const int NK = K / 32;
#pragma unroll
  for (int ks = 0; ks < NK; ks++) {
    const int buf = ks & 1;
    __syncthreads();  // drains this wave's stage(buf) + orders prev compute
    if (ks + 1 < NK) stage(buf ^ 1, (ks + 1) * 32);

    short8 fa[4], fbh[4];
#pragma unroll
    for (int r = 0; r < 4; r++)
      fa[r] = *(const short8*)(&Asb[buf][wr + r * 16 + fr][fq * 8]);
#pragma unroll
    for (int c = 0; c < 4; c++)
      fbh[c] = *(const short8*)(&Bhb[buf][wc + c * 16 + fr][fq * 8]);
#pragma unroll
    for (int r = 0; r < 4; r++)
#pragma unroll
      for (int c = 0; c < 4; c++)
        acc[r][c] = __builtin_amdgcn_mfma_f32_16x16x32_bf16(fa[r], fbh[c], acc[r][c], 0, 0, 0);
  }

  // ---- C write (fp8 e4m3; L2 absorbs the 1B scatter)
#pragma unroll
  for (int r = 0; r < 4; r++)
#pragma unroll
    for (int c = 0; c < 4; c++) {
      int colg = col0 + wc + c * 16 + fr;
#pragma unroll
      for (int reg = 0; reg < 4; reg++) {
        int gr = row0 + wr + r * 16 + fq * 4 + reg;
        if (gr < Nrows)
          hout[(size_t)gr * 256 + colg] = f2fp8(acc[r][c][reg]);
      }
    }

  // ---- attention scores: wave's 64 cols = one head (wc 64-aligned)
  const int head = (col0 + wc) >> 6;
  float asv[4], adv[4];
#pragma unroll
  for (int c = 0; c < 4; c++) {
    asv[c] = att_s[col0 + wc + c * 16 + fr];
    adv[c] = att_d[col0 + wc + c * 16 + fr];
  }
#pragma unroll
  for (int r = 0; r < 4; r++)
#pragma unroll
    for (int reg = 0; reg < 4; reg++) {
      float ps = 0.f, pd = 0.f;
#pragma unroll
      for (int c = 0; c < 4; c++) {
        ps += acc[r][c][reg] * asv[c];
        pd += acc[r][c][reg] * adv[c];
      }
      ps += __shfl_xor(ps, 1); pd += __shfl_xor(pd, 1);
      ps += __shfl_xor(ps, 2); pd += __shfl_xor(pd, 2);
      ps += __shfl_xor(ps, 4); pd += __shfl_xor(pd, 4);
      ps += __shfl_xor(ps, 8); pd += __shfl_xor(pd, 8);
      if (fr == 0) {
        int gr = row0 + wr + r * 16 + fq * 4 + reg;
        if (gr < Nrows) {
          a_s[(size_t)gr * 4 + head] = ps;
          a_d[(size_t)gr * 4 + head] = pd;
        }
      }
    }
}

// ---- fused: gemm1 blocks first, dependency-free scatter backfill ----------
// Scatter: 4 edges/thread (1024/block). dst/pe/src all COALESCED reads;
// scattered col2 stores have no in-kernel dependency (pe precomputed).
__global__ __launch_bounds__(256)
void k_gemm1_scatter(const ushort* __restrict__ xb,
                     const ushort* __restrict__ Bt,
                     unsigned char* __restrict__ hout, int Nrows,
                     const float* __restrict__ att_s,
                     const float* __restrict__ att_d,
                     float* __restrict__ a_s, float* __restrict__ a_d,
                     const int* __restrict__ srcv, const int* __restrict__ dstv,
                     const int* __restrict__ pe, int* __restrict__ col2,
                     int E, int gemm_blocks) {
  if ((int)blockIdx.x < gemm_blocks) {
    gemm_body<128>(blockIdx.x, xb, Bt, hout, Nrows,
                   att_s, att_d, a_s, a_d);
  } else {
    int base = ((int)blockIdx.x - gemm_blocks) * 1024 + threadIdx.x;
#pragma unroll
    for (int k = 0; k < 4; k++) {
      int i = base + k * 256;
      if (i < E) {
        int s = pe[i];
        if (s < 64) col2[(dstv[i] << 6) + s] = srcv[i] << 8;
      }
    }
  }
}

__global__ __launch_bounds__(256)
void k_gemm2(const ushort* __restrict__ Ah,
             const ushort* __restrict__ Bt,
             unsigned char* __restrict__ hout, int Nrows,
             const float* __restrict__ att_s, const float* __restrict__ att_d,
             float* __restrict__ a_s, float* __restrict__ a_d) {
  gemm_body<256>(blockIdx.x, Ah, Bt, hout, Nrows,
                 att_s, att_d, a_s, a_d);
}

// ----------------------------- aggregation ---------------------------------
// ONE wave per node; lane owns channels [4*lane, 4*lane+3], head = lane>>4.
// h is FP8 e4m3 for BOTH layers: 4 B/lane gather (256 B/edge), HW cvt decode.
// Padded adjacency: deg = min(cnt[node],64); col2[node<<6 + j] = src*256.
// acc in 2x f32x2 (v_pk_fma_f32). Edge loop unrolled 8/4/1.
// LAYER 1: relu(acc/den + bias) -> plain bf16.
// LAYER 2: fused finale — head-mean + bias + relu + softmax(64) -> outp.
template <int LAYER>
__global__ __launch_bounds__(256)
void k_aggr(const unsigned char* __restrict__ hsrc,
            const int* __restrict__ cnt, const int* __restrict__ col2,
            const float* __restrict__ a_s, const float* __restrict__ a_d,
            const float* __restrict__ bias,
            ushort* __restrict__ out_h, float* __restrict__ outp, int N) {
  __shared__ int   s_sh[4][64];
  __shared__ float w_sh[4][256];
  const int wv = threadIdx.x >> 6;
  const int lane = threadIdx.x & 63;
  const int node = blockIdx.x * 4 + wv;
  if (node >= N) return;
  const int hd = lane >> 4;
  const int deg = min(cnt[node], 64);
  const int beg = node << 6;
  const float4 adst = *(const float4*)(a_d + (size_t)node * 4);

  f32x2 accA = {0.f, 0.f};   // channels lane*4+0, +1
  f32x2 accB = {0.f, 0.f};   // channels lane*4+2, +3
  float wsum = 0.f;
  const char* hbase = (const char*)hsrc + lane * 4;  // 256 B row stride

  {
    int nc = deg;              // deg <= 64: exactly one 64-wide pass
    int off = 0;
    float4 w4 = make_float4(0.f, 0.f, 0.f, 0.f);
    if (lane < nc) {
      off = col2[beg + lane];  // src*256
      const float4 a = *(const float4*)((const char*)a_s + (size_t)((uint)off >> 4));
      float e0 = a.x + adst.x; e0 = e0 > 0.f ? e0 : 0.2f * e0;
      float e1 = a.y + adst.y; e1 = e1 > 0.f ? e1 : 0.2f * e1;
      float e2 = a.z + adst.z; e2 = e2 > 0.f ? e2 : 0.2f * e2;
      float e3 = a.w + adst.w; e3 = e3 > 0.f ? e3 : 0.2f * e3;
      w4 = make_float4(__expf(e0), __expf(e1), __expf(e2), __expf(e3));
    }
    s_sh[wv][lane] = off;
    *(float4*)(&w_sh[wv][lane * 4]) = w4;
    asm volatile("s_waitcnt lgkmcnt(0)" ::: "memory");

    const float* wrow = &w_sh[wv][hd];
    const int*   srow = &s_sh[wv][0];
    int j = 0;
    for (; j + 8 <= nc; j += 8) {
      int o0 = srow[j],     o1 = srow[j + 1], o2 = srow[j + 2], o3 = srow[j + 3];
      int o4 = srow[j + 4], o5 = srow[j + 5], o6 = srow[j + 6], o7 = srow[j + 7];
      float ww0 = wrow[4 * j],      ww1 = wrow[4 * j + 4];
      float ww2 = wrow[4 * j + 8],  ww3 = wrow[4 * j + 12];
      float ww4 = wrow[4 * j + 16], ww5 = wrow[4 * j + 20];
      float ww6 = wrow[4 * j + 24], ww7 = wrow[4 * j + 28];
      uint p0 = *(const uint*)(hbase + (size_t)(uint)o0);
      uint p1 = *(const uint*)(hbase + (size_t)(uint)o1);
      uint p2 = *(const uint*)(hbase + (size_t)(uint)o2);
      uint p3 = *(const uint*)(hbase + (size_t)(uint)o3);
      uint p4 = *(const uint*)(hbase + (size_t)(uint)o4);
      uint p5 = *(const uint*)(hbase + (size_t)(uint)o5);
      uint p6 = *(const uint*)(hbase + (size_t)(uint)o6);
      uint p7 = *(const uint*)(hbase + (size_t)(uint)o7);
      wsum += ww0 + ww1 + ww2 + ww3;
      wsum += ww4 + ww5 + ww6 + ww7;
      f32x2 W;
#define EDGE_FMA(ww, p)                                                     \
      {                                                                     \
        f32x2 lo = __builtin_amdgcn_cvt_pk_f32_fp8((p), false);             \
        f32x2 hi = __builtin_amdgcn_cvt_pk_f32_fp8((p), true);              \
        W.x = (ww); W.y = (ww);                                             \
        accA = __builtin_elementwise_fma(W, lo, accA);                      \
        accB = __builtin_elementwise_fma(W, hi, accB);                      \
      }
      EDGE_FMA(ww0, p0) EDGE_FMA(ww1, p1) EDGE_FMA(ww2, p2) EDGE_FMA(ww3, p3)
      EDGE_FMA(ww4, p4) EDGE_FMA(ww5, p5) EDGE_FMA(ww6, p6) EDGE_FMA(ww7, p7)
    }
    for (; j + 4 <= nc; j += 4) {
      int o0 = srow[j], o1 = srow[j + 1], o2 = srow[j + 2], o3 = srow[j + 3];
      float ww0 = wrow[4 * j],     ww1 = wrow[4 * j + 4];
      float ww2 = wrow[4 * j + 8], ww3 = wrow[4 * j + 12];
      uint p0 = *(const uint*)(hbase + (size_t)(uint)o0);
      uint p1 = *(const uint*)(hbase + (size_t)(uint)o1);
      uint p2 = *(const uint*)(hbase + (size_t)(uint)o2);
      uint p3 = *(const uint*)(hbase + (size_t)(uint)o3);
      wsum += ww0 + ww1 + ww2 + ww3;
      f32x2 W;
      EDGE_FMA(ww0, p0) EDGE_FMA(ww1, p1) EDGE_FMA(ww2, p2) EDGE_FMA(ww3, p3)
    }
    for (; j < nc; j++) {
      int o = srow[j];
      float ww = wrow[4 * j];
      uint p = *(const uint*)(hbase + (size_t)(uint)o);
      wsum += ww;
      f32x2 W;
      EDGE_FMA(ww, p)
    }
#undef EDGE_FMA
  }

  float inv = 1.0f / wsum;  // deg>=1 via self-loop
  float4 v = make_float4(accA.x * inv, accA.y * inv, accB.x * inv, accB.y * inv);

  if (LAYER == 1) {
    const float4 bv = *(const float4*)(bias + lane * 4);
    v.x = fmaxf(v.x + bv.x, 0.f);
    v.y = fmaxf(v.y + bv.y, 0.f);
    v.z = fmaxf(v.z + bv.z, 0.f);
    v.w = fmaxf(v.w + bv.w, 0.f);
    ushort4 h;
    h.x = f2bf(v.x); h.y = f2bf(v.y); h.z = f2bf(v.z); h.w = f2bf(v.w);
    *(ushort4*)(out_h + (size_t)node * 256 + lane * 4) = h;
  } else {
    // fused finale: head-mean + bias + relu + softmax(64)
    v.x += __shfl_xor(v.x, 16); v.y += __shfl_xor(v.y, 16);
    v.z += __shfl_xor(v.z, 16); v.w += __shfl_xor(v.w, 16);
    v.x += __shfl_xor(v.x, 32); v.y += __shfl_xor(v.y, 32);
    v.z += __shfl_xor(v.z, 32); v.w += __shfl_xor(v.w, 32);
    const int c4 = (lane & 15) * 4;
    const float4 bv = *(const float4*)(bias + c4);
    v.x = fmaxf(v.x * 0.25f + bv.x, 0.f);
    v.y = fmaxf(v.y * 0.25f + bv.y, 0.f);
    v.z = fmaxf(v.z * 0.25f + bv.z, 0.f);
    v.w = fmaxf(v.w * 0.25f + bv.w, 0.f);
    float mx = fmaxf(fmaxf(v.x, v.y), fmaxf(v.z, v.w));
    for (int off = 8; off >= 1; off >>= 1) mx = fmaxf(mx, __shfl_xor(mx, off));
    v.x = __expf(v.x - mx); v.y = __expf(v.y - mx);
    v.z = __expf(v.z - mx); v.w = __expf(v.w - mx);
    float sum = v.x + v.y + v.z + v.w;
    for (int off = 8; off >= 1; off >>= 1) sum += __shfl_xor(sum, off);
    float is = 1.0f / sum;
    v.x *= is; v.y *= is; v.z *= is; v.w *= is;
    if (lane < 16) *(float4*)(outp + (size_t)node * 64 + c4) = v;
  }
}

// ---------------------------------------------------------------------------

extern "C" void kernel_launch(void* const* d_in, const int* in_sizes, int n_in,
                              void* d_out, int out_size, void* d_ws, size_t ws_size,
                              hipStream_t stream) {
  const float* x   = (const float*)d_in[0];
  const int*   ei  = (const int*)d_in[1];
  const float* W1  = (const float*)d_in[2];
  const float* as1 = (const float*)d_in[3];
  const float* ad1 = (const float*)d_in[4];
  const float* b1  = (const float*)d_in[5];
  const float* W2  = (const float*)d_in[6];
  const float* as2 = (const float*)d_in[7];
  const float* ad2 = (const float*)d_in[8];
  const float* b2  = (const float*)d_in[9];
  float* out = (float*)d_out;

  const int N = in_sizes[0] / 128;
  const int E = in_sizes[1] / 2;
  const int* srcv = ei;
  const int* dstv = ei + E;

  // ---- workspace layout
  unsigned char* h8 = (unsigned char*)d_ws;       // [N,256] fp8 (both layers)
  ushort* hb   = (ushort*)(h8 + (size_t)N * 256); // [N,256] bf16 (aggr1 out)
  ushort* w1t  = hb + (size_t)N * 256;            // [256][128] bf16
  ushort* w2t  = w1t + 256 * 128;                 // [256][256] bf16
  float*  zbuf = (float*)(w2t + 256 * 256);       // a_s1,a_d1,a_s2,a_d2 [16N]
  float* a_s1 = zbuf;
  float* a_d1 = a_s1 + (size_t)N * 4;
  float* a_s2 = a_d1 + (size_t)N * 4;
  float* a_d2 = a_s2 + (size_t)N * 4;
  int* cnt    = (int*)(zbuf + (size_t)N * 16);    // [N]  (memset region)
  int* col2   = cnt + N;                          // [N*64] padded adjacency
  int* pe     = col2 + (size_t)N * 64;            // [E] per-edge slot
  ushort* xb  = (ushort*)(pe + E);                // [N,128] bf16 of x

  const int eb  = (E + 255) / 256;    // 1 edge/thread hist blocks (R26 form)
  const int eb4 = (E + 1023) / 1024;  // 4 edges/thread scatter blocks
  const int ng = N * 16;              // x-conversion groups (8 elems each)
  const int xcb = (ng + 255) / 256;   // x-conversion blocks

  // XCD-aligned swizzled 1-D grid: 16 blocks per group of 8 row blocks
  const int nrb = (N + 127) / 128;
  const int gemm_blocks = ((nrb + 7) / 8) * 16;
  const int wb = (N + 3) / 4;  // one wave per node

  hipMemsetAsync(cnt, 0, (size_t)N * 4, stream);
  k_prep_hist<<<384 + eb + xcb, 256, 0, stream>>>(
      W1, W2, w1t, w2t, dstv, cnt, pe, E, x, xb, ng);
  k_gemm1_scatter<<<gemm_blocks + eb4, 256, 0, stream>>>(
      xb, w1t, h8, N, as1, ad1, a_s1, a_d1,
      srcv, dstv, pe, col2, E, gemm_blocks);
  k_aggr<1><<<wb, 256, 0, stream>>>(h8, cnt, col2, a_s1, a_d1, b1,
                                    hb, nullptr, N);
  k_gemm2<<<gemm_blocks, 256, 0, stream>>>(hb, w2t, h8, N,
                                           as2, ad2, a_s2, a_d2);
  k_aggr<2><<<wb, 256, 0, stream>>>(h8, cnt, col2, a_s2, a_d2, b2,
                                    nullptr, out, N);
}

// Round 15
// 247.641 us; speedup vs baseline: 1.0892x; 1.0195x over previous
//
#include <hip/hip_runtime.h>

// ---------------------------------------------------------------------------
// 2-layer GAT (PyG GATConv), MI355X.
// R36 (from R35 = 252.5us; k_prep_hist 43.3us @ occ 69%, VALU 1.7%, HBM 17%
//      -> hist is TCC-SERIALIZATION-bound, not latency/parallelism-bound):
//   (1) cnt padded to ONE COUNTER PER 64B LINE (cnt[d<<4]): 16 counters per
//       line previously -> ~272 atomic collisions/line; padding cuts
//       line-level serialization 16x. memset now 3.2MB (~0.5us).
//   (2) hist blocks FIRST in prep kernel (they're the 43us long pole; the
//       384 W-prep blocks were delaying hist start in R35).
//   Everything else byte-frozen from R35 (pe-split scatter in gemm1,
//   1-term gemm, padded adjacency, R26 aggr).
// ---------------------------------------------------------------------------

typedef __attribute__((ext_vector_type(8))) short short8;
typedef __attribute__((ext_vector_type(4))) float f32x4;
typedef __attribute__((ext_vector_type(2))) float f32x2;

static __device__ __forceinline__ ushort f2bf(float f) {  // RNE
  uint u = __float_as_uint(f);
  return (ushort)((u + 0x7FFFu + ((u >> 16) & 1u)) >> 16);
}
static __device__ __forceinline__ float bf2f(ushort s) {
  return __uint_as_float(((uint)s) << 16);
}
static __device__ __forceinline__ unsigned char f2fp8(float f) {  // e4m3 (HW)
  int p = __builtin_amdgcn_cvt_pk_fp8_f32(f, f, 0, false);
  return (unsigned char)(p & 0xFF);
}
static __device__ __forceinline__ uint4 cvt8bf(const float4& a, const float4& b) {
  uint4 hh;
  hh.x = (uint)f2bf(a.x) | ((uint)f2bf(a.y) << 16);
  hh.y = (uint)f2bf(a.z) | ((uint)f2bf(a.w) << 16);
  hh.z = (uint)f2bf(b.x) | ((uint)f2bf(b.y) << 16);
  hh.w = (uint)f2bf(b.z) | ((uint)f2bf(b.w) << 16);
  return hh;
}
// async global->LDS, 16B per lane (wave-uniform LDS base + lane*16)
static __device__ __forceinline__ void gl16(const ushort* g, ushort* l) {
  __builtin_amdgcn_global_load_lds(
      (const __attribute__((address_space(1))) uint*)(g),
      (__attribute__((address_space(3))) uint*)(l), 16, 0, 0);
}

// ---- hist FIRST (line-padded cnt), then W-prep + x->bf16 ------------------
// Hist: 1 edge/thread; atomic return = edge's slot, written COALESCED to pe.
// cnt[d<<4]: one counter per 64B line (16x less line-level serialization).
__global__ __launch_bounds__(256)
void k_prep_hist(const float* __restrict__ W1, const float* __restrict__ W2,
                 ushort* __restrict__ w1t, ushort* __restrict__ w2t,
                 const int* __restrict__ dstv, int* __restrict__ cnt,
                 int* __restrict__ pe, int E,
                 const float* __restrict__ x, ushort* __restrict__ xb,
                 int ng) {
  const int b = blockIdx.x;
  const int eb = (E + 255) >> 8;
  if (b < eb) {  // histogram; atomic return = edge's slot (pe)
    int i = b * 256 + threadIdx.x;
    if (i < E) pe[i] = atomicAdd(&cnt[(size_t)dstv[i] << 4], 1);
  } else if (b < eb + 128) {  // W1 [128][256] -> [256][128] bf16
    int gid = (b - eb) * 256 + threadIdx.x;
    int c = gid & 255, k = gid >> 8;
    w1t[(size_t)c * 128 + k] = f2bf(W1[(size_t)k * 256 + c]);
  } else if (b < eb + 384) {  // W2 [256][256] -> [256][256] bf16
    int gid = (b - eb - 128) * 256 + threadIdx.x;
    int c = gid & 255, k = gid >> 8;
    w2t[(size_t)c * 256 + k] = f2bf(W2[(size_t)k * 256 + c]);
  } else {  // x fp32 -> bf16 (RNE), 8 elems/thread
    int i = (b - eb - 384) * 256 + threadIdx.x;
    if (i < ng) {
      const float4* xp = (const float4*)x + (size_t)i * 2;
      float4 a = xp[0], bb = xp[1];
      ((uint4*)xb)[i] = cvt8bf(a, bb);
    }
  }
}

// ----------------------------- MFMA GEMM body ------------------------------
// 256 threads / 4 waves; block tile 128 rows x 128 cols (col-half of C).
// Wave tile 64x64: wr=(w>>1)*64, wc=(w&1)*64; acc[4][4].
// Async-staged double-buffered LDS via global_load_lds; one __syncthreads
// per K-step; next stage issued right after the barrier. Single-term
// (plain bf16 W): A + B tiles only, LDS 32KB -> 5 blocks/CU.
// C[N,256] = A_bf16 @ B[K,256], Bt stored [256][K]. C -> FP8 e4m3.
// XCD-aligned swizzle: col-halves of a row block differ by 8 block ids.
template <int K>
static __device__ __forceinline__
void gemm_body(int bid, const ushort* __restrict__ Ah,
               const ushort* __restrict__ Bt,
               unsigned char* __restrict__ hout, int Nrows,
               const float* __restrict__ att_s, const float* __restrict__ att_d,
               float* __restrict__ a_s, float* __restrict__ a_d) {
  __shared__ ushort Asb[2][128][32];
  __shared__ ushort Bhb[2][128][32];

  const int nrb = (Nrows + 127) >> 7;
  const int rb = (bid >> 4) * 8 + (bid & 7);
  const int ch = (bid >> 3) & 1;
  if (rb >= nrb) return;
  const int row0 = rb * 128;
  const int col0 = ch * 128;

  const int t = threadIdx.x;
  const int lane = t & 63;
  const int w = t >> 6;            // 0..3
  const int wr = (w >> 1) * 64;
  const int wc = (w & 1) * 64;
  const int fr = lane & 15;
  const int fq = lane >> 4;

  // staging source addresses (per-lane)
  const int srow = lane >> 2;          // 0..15
  const int skc = (lane & 3) * 8;      // k offset in elems
  int ar0 = row0 + w * 32 + srow;
  int ar1 = ar0 + 16;
  ar0 = ar0 < Nrows ? ar0 : Nrows - 1;  // clamped tail (stores guarded later)
  ar1 = ar1 < Nrows ? ar1 : Nrows - 1;
  const ushort* agp0 = Ah + (size_t)ar0 * K + skc;
  const ushort* agp1 = Ah + (size_t)ar1 * K + skc;
  const ushort* bhg0 = Bt + (size_t)(col0 + w * 32 + srow) * K + skc;
  const ushort* bhg1 = bhg0 + (size_t)16 * K;

  f32x4 acc[4][4] = {};

  auto stage = [&](int buf, int k0) {
    gl16(agp0 + k0, &Asb[buf][w * 32][0]);
    gl16(agp1 + k0, &Asb[buf][w * 32 + 16][0]);
    gl16(bhg0 + k0, &Bhb[buf][w * 32][0]);
    gl16(bhg1 + k0, &Bhb[buf][w * 32 + 16][0]);
  };

  stage(0, 0);
  const int NK = K / 32;
#pragma unroll
  for (int ks = 0; ks < NK; ks++) {
    const int buf = ks & 1;
    __syncthreads();  // drains this wave's stage(buf) + orders prev compute
    if (ks + 1 < NK) stage(buf ^ 1, (ks + 1) * 32);

    short8 fa[4], fbh[4];
#pragma unroll
    for (int r = 0; r < 4; r++)
      fa[r] = *(const short8*)(&Asb[buf][wr + r * 16 + fr][fq * 8]);
#pragma unroll
    for (int c = 0; c < 4; c++)
      fbh[c] = *(const short8*)(&Bhb[buf][wc + c * 16 + fr][fq * 8]);
#pragma unroll
    for (int r = 0; r < 4; r++)
#pragma unroll
      for (int c = 0; c < 4; c++)
        acc[r][c] = __builtin_amdgcn_mfma_f32_16x16x32_bf16(fa[r], fbh[c], acc[r][c], 0, 0, 0);
  }

  // ---- C write (fp8 e4m3; L2 absorbs the 1B scatter)
#pragma unroll
  for (int r = 0; r < 4; r++)
#pragma unroll
    for (int c = 0; c < 4; c++) {
      int colg = col0 + wc + c * 16 + fr;
#pragma unroll
      for (int reg = 0; reg < 4; reg++) {
        int gr = row0 + wr + r * 16 + fq * 4 + reg;
        if (gr < Nrows)
          hout[(size_t)gr * 256 + colg] = f2fp8(acc[r][c][reg]);
      }
    }

  // ---- attention scores: wave's 64 cols = one head (wc 64-aligned)
  const int head = (col0 + wc) >> 6;
  float asv[4], adv[4];
#pragma unroll
  for (int c = 0; c < 4; c++) {
    asv[c] = att_s[col0 + wc + c * 16 + fr];
    adv[c] = att_d[col0 + wc + c * 16 + fr];
  }
#pragma unroll
  for (int r = 0; r < 4; r++)
#pragma unroll
    for (int reg = 0; reg < 4; reg++) {
      float ps = 0.f, pd = 0.f;
#pragma unroll
      for (int c = 0; c < 4; c++) {
        ps += acc[r][c][reg] * asv[c];
        pd += acc[r][c][reg] * adv[c];
      }
      ps += __shfl_xor(ps, 1); pd += __shfl_xor(pd, 1);
      ps += __shfl_xor(ps, 2); pd += __shfl_xor(pd, 2);
      ps += __shfl_xor(ps, 4); pd += __shfl_xor(pd, 4);
      ps += __shfl_xor(ps, 8); pd += __shfl_xor(pd, 8);
      if (fr == 0) {
        int gr = row0 + wr + r * 16 + fq * 4 + reg;
        if (gr < Nrows) {
          a_s[(size_t)gr * 4 + head] = ps;
          a_d[(size_t)gr * 4 + head] = pd;
        }
      }
    }
}

// ---- fused: gemm1 blocks first, dependency-free scatter backfill ----------
// Scatter: 4 edges/thread (1024/block). dst/pe/src all COALESCED reads;
// scattered col2 stores have no in-kernel dependency (pe precomputed).
__global__ __launch_bounds__(256)
void k_gemm1_scatter(const ushort* __restrict__ xb,
                     const ushort* __restrict__ Bt,
                     unsigned char* __restrict__ hout, int Nrows,
                     const float* __restrict__ att_s,
                     const float* __restrict__ att_d,
                     float* __restrict__ a_s, float* __restrict__ a_d,
                     const int* __restrict__ srcv, const int* __restrict__ dstv,
                     const int* __restrict__ pe, int* __restrict__ col2,
                     int E, int gemm_blocks) {
  if ((int)blockIdx.x < gemm_blocks) {
    gemm_body<128>(blockIdx.x, xb, Bt, hout, Nrows,
                   att_s, att_d, a_s, a_d);
  } else {
    int base = ((int)blockIdx.x - gemm_blocks) * 1024 + threadIdx.x;
#pragma unroll
    for (int k = 0; k < 4; k++) {
      int i = base + k * 256;
      if (i < E) {
        int s = pe[i];
        if (s < 64) col2[(dstv[i] << 6) + s] = srcv[i] << 8;
      }
    }
  }
}

__global__ __launch_bounds__(256)
void k_gemm2(const ushort* __restrict__ Ah,
             const ushort* __restrict__ Bt,
             unsigned char* __restrict__ hout, int Nrows,
             const float* __restrict__ att_s, const float* __restrict__ att_d,
             float* __restrict__ a_s, float* __restrict__ a_d) {
  gemm_body<256>(blockIdx.x, Ah, Bt, hout, Nrows,
                 att_s, att_d, a_s, a_d);
}

// ----------------------------- aggregation ---------------------------------
// ONE wave per node; lane owns channels [4*lane, 4*lane+3], head = lane>>4.
// h is FP8 e4m3 for BOTH layers: 4 B/lane gather (256 B/edge), HW cvt decode.
// Padded adjacency: deg = min(cnt[node<<4],64); col2[node<<6 + j] = src*256.
// acc in 2x f32x2 (v_pk_fma_f32). Edge loop unrolled 8/4/1.
// LAYER 1: relu(acc/den + bias) -> plain bf16.
// LAYER 2: fused finale — head-mean + bias + relu + softmax(64) -> outp.
template <int LAYER>
__global__ __launch_bounds__(256)
void k_aggr(const unsigned char* __restrict__ hsrc,
            const int* __restrict__ cnt, const int* __restrict__ col2,
            const float* __restrict__ a_s, const float* __restrict__ a_d,
            const float* __restrict__ bias,
            ushort* __restrict__ out_h, float* __restrict__ outp, int N) {
  __shared__ int   s_sh[4][64];
  __shared__ float w_sh[4][256];
  const int wv = threadIdx.x >> 6;
  const int lane = threadIdx.x & 63;
  const int node = blockIdx.x * 4 + wv;
  if (node >= N) return;
  const int hd = lane >> 4;
  const int deg = min(cnt[(size_t)node << 4], 64);
  const int beg = node << 6;
  const float4 adst = *(const float4*)(a_d + (size_t)node * 4);

  f32x2 accA = {0.f, 0.f};   // channels lane*4+0, +1
  f32x2 accB = {0.f, 0.f};   // channels lane*4+2, +3
  float wsum = 0.f;
  const char* hbase = (const char*)hsrc + lane * 4;  // 256 B row stride

  {
    int nc = deg;              // deg <= 64: exactly one 64-wide pass
    int off = 0;
    float4 w4 = make_float4(0.f, 0.f, 0.f, 0.f);
    if (lane < nc) {
      off = col2[beg + lane];  // src*256
      const float4 a = *(const float4*)((const char*)a_s + (size_t)((uint)off >> 4));
      float e0 = a.x + adst.x; e0 = e0 > 0.f ? e0 : 0.2f * e0;
      float e1 = a.y + adst.y; e1 = e1 > 0.f ? e1 : 0.2f * e1;
      float e2 = a.z + adst.z; e2 = e2 > 0.f ? e2 : 0.2f * e2;
      float e3 = a.w + adst.w; e3 = e3 > 0.f ? e3 : 0.2f * e3;
      w4 = make_float4(__expf(e0), __expf(e1), __expf(e2), __expf(e3));
    }
    s_sh[wv][lane] = off;
    *(float4*)(&w_sh[wv][lane * 4]) = w4;
    asm volatile("s_waitcnt lgkmcnt(0)" ::: "memory");

    const float* wrow = &w_sh[wv][hd];
    const int*   srow = &s_sh[wv][0];
    int j = 0;
    for (; j + 8 <= nc; j += 8) {
      int o0 = srow[j],     o1 = srow[j + 1], o2 = srow[j + 2], o3 = srow[j + 3];
      int o4 = srow[j + 4], o5 = srow[j + 5], o6 = srow[j + 6], o7 = srow[j + 7];
      float ww0 = wrow[4 * j],      ww1 = wrow[4 * j + 4];
      float ww2 = wrow[4 * j + 8],  ww3 = wrow[4 * j + 12];
      float ww4 = wrow[4 * j + 16], ww5 = wrow[4 * j + 20];
      float ww6 = wrow[4 * j + 24], ww7 = wrow[4 * j + 28];
      uint p0 = *(const uint*)(hbase + (size_t)(uint)o0);
      uint p1 = *(const uint*)(hbase + (size_t)(uint)o1);
      uint p2 = *(const uint*)(hbase + (size_t)(uint)o2);
      uint p3 = *(const uint*)(hbase + (size_t)(uint)o3);
      uint p4 = *(const uint*)(hbase + (size_t)(uint)o4);
      uint p5 = *(const uint*)(hbase + (size_t)(uint)o5);
      uint p6 = *(const uint*)(hbase + (size_t)(uint)o6);
      uint p7 = *(const uint*)(hbase + (size_t)(uint)o7);
      wsum += ww0 + ww1 + ww2 + ww3;
      wsum += ww4 + ww5 + ww6 + ww7;
      f32x2 W;
#define EDGE_FMA(ww, p)                                                     \
      {                                                                     \
        f32x2 lo = __builtin_amdgcn_cvt_pk_f32_fp8((p), false);             \
        f32x2 hi = __builtin_amdgcn_cvt_pk_f32_fp8((p), true);              \
        W.x = (ww); W.y = (ww);                                             \
        accA = __builtin_elementwise_fma(W, lo, accA);                      \
        accB = __builtin_elementwise_fma(W, hi, accB);                      \
      }
      EDGE_FMA(ww0, p0) EDGE_FMA(ww1, p1) EDGE_FMA(ww2, p2) EDGE_FMA(ww3, p3)
      EDGE_FMA(ww4, p4) EDGE_FMA(ww5, p5) EDGE_FMA(ww6, p6) EDGE_FMA(ww7, p7)
    }
    for (; j + 4 <= nc; j += 4) {
      int o0 = srow[j], o1 = srow[j + 1], o2 = srow[j + 2], o3 = srow[j + 3];
      float ww0 = wrow[4 * j],     ww1 = wrow[4 * j + 4];
      float ww2 = wrow[4 * j + 8], ww3 = wrow[4 * j + 12];
      uint p0 = *(const uint*)(hbase + (size_t)(uint)o0);
      uint p1 = *(const uint*)(hbase + (size_t)(uint)o1);
      uint p2 = *(const uint*)(hbase + (size_t)(uint)o2);
      uint p3 = *(const uint*)(hbase + (size_t)(uint)o3);
      wsum += ww0 + ww1 + ww2 + ww3;
      f32x2 W;
      EDGE_FMA(ww0, p0) EDGE_FMA(ww1, p1) EDGE_FMA(ww2, p2) EDGE_FMA(ww3, p3)
    }
    for (; j < nc; j++) {
      int o = srow[j];
      float ww = wrow[4 * j];
      uint p = *(const uint*)(hbase + (size_t)(uint)o);
      wsum += ww;
      f32x2 W;
      EDGE_FMA(ww, p)
    }
#undef EDGE_FMA
  }

  float inv = 1.0f / wsum;  // deg>=1 via self-loop
  float4 v = make_float4(accA.x * inv, accA.y * inv, accB.x * inv, accB.y * inv);

  if (LAYER == 1) {
    const float4 bv = *(const float4*)(bias + lane * 4);
    v.x = fmaxf(v.x + bv.x, 0.f);
    v.y = fmaxf(v.y + bv.y, 0.f);
    v.z = fmaxf(v.z + bv.z, 0.f);
    v.w = fmaxf(v.w + bv.w, 0.f);
    ushort4 h;
    h.x = f2bf(v.x); h.y = f2bf(v.y); h.z = f2bf(v.z); h.w = f2bf(v.w);
    *(ushort4*)(out_h + (size_t)node * 256 + lane * 4) = h;
  } else {
    // fused finale: head-mean + bias + relu + softmax(64)
    v.x += __shfl_xor(v.x, 16); v.y += __shfl_xor(v.y, 16);
    v.z += __shfl_xor(v.z, 16); v.w += __shfl_xor(v.w, 16);
    v.x += __shfl_xor(v.x, 32); v.y += __shfl_xor(v.y, 32);
    v.z += __shfl_xor(v.z, 32); v.w += __shfl_xor(v.w, 32);
    const int c4 = (lane & 15) * 4;
    const float4 bv = *(const float4*)(bias + c4);
    v.x = fmaxf(v.x * 0.25f + bv.x, 0.f);
    v.y = fmaxf(v.y * 0.25f + bv.y, 0.f);
    v.z = fmaxf(v.z * 0.25f + bv.z, 0.f);
    v.w = fmaxf(v.w * 0.25f + bv.w, 0.f);
    float mx = fmaxf(fmaxf(v.x, v.y), fmaxf(v.z, v.w));
    for (int off = 8; off >= 1; off >>= 1) mx = fmaxf(mx, __shfl_xor(mx, off));
    v.x = __expf(v.x - mx); v.y = __expf(v.y - mx);
    v.z = __expf(v.z - mx); v.w = __expf(v.w - mx);
    float sum = v.x + v.y + v.z + v.w;
    for (int off = 8; off >= 1; off >>= 1) sum += __shfl_xor(sum, off);
    float is = 1.0f / sum;
    v.x *= is; v.y *= is; v.z *= is; v.w *= is;
    if (lane < 16) *(float4*)(outp + (size_t)node * 64 + c4) = v;
  }
}

// ---------------------------------------------------------------------------

extern "C" void kernel_launch(void* const* d_in, const int* in_sizes, int n_in,
                              void* d_out, int out_size, void* d_ws, size_t ws_size,
                              hipStream_t stream) {
  const float* x   = (const float*)d_in[0];
  const int*   ei  = (const int*)d_in[1];
  const float* W1  = (const float*)d_in[2];
  const float* as1 = (const float*)d_in[3];
  const float* ad1 = (const float*)d_in[4];
  const float* b1  = (const float*)d_in[5];
  const float* W2  = (const float*)d_in[6];
  const float* as2 = (const float*)d_in[7];
  const float* ad2 = (const float*)d_in[8];
  const float* b2  = (const float*)d_in[9];
  float* out = (float*)d_out;

  const int N = in_sizes[0] / 128;
  const int E = in_sizes[1] / 2;
  const int* srcv = ei;
  const int* dstv = ei + E;

  // ---- workspace layout
  unsigned char* h8 = (unsigned char*)d_ws;       // [N,256] fp8 (both layers)
  ushort* hb   = (ushort*)(h8 + (size_t)N * 256); // [N,256] bf16 (aggr1 out)
  ushort* w1t  = hb + (size_t)N * 256;            // [256][128] bf16
  ushort* w2t  = w1t + 256 * 128;                 // [256][256] bf16
  float*  zbuf = (float*)(w2t + 256 * 256);       // a_s1,a_d1,a_s2,a_d2 [16N]
  float* a_s1 = zbuf;
  float* a_d1 = a_s1 + (size_t)N * 4;
  float* a_s2 = a_d1 + (size_t)N * 4;
  float* a_d2 = a_s2 + (size_t)N * 4;
  int* cnt    = (int*)(zbuf + (size_t)N * 16);    // [N*16] line-padded (memset)
  int* col2   = cnt + (size_t)N * 16;             // [N*64] padded adjacency
  int* pe     = col2 + (size_t)N * 64;            // [E] per-edge slot
  ushort* xb  = (ushort*)(pe + E);                // [N,128] bf16 of x

  const int eb  = (E + 255) / 256;    // 1 edge/thread hist blocks
  const int eb4 = (E + 1023) / 1024;  // 4 edges/thread scatter blocks
  const int ng = N * 16;              // x-conversion groups (8 elems each)
  const int xcb = (ng + 255) / 256;   // x-conversion blocks

  // XCD-aligned swizzled 1-D grid: 16 blocks per group of 8 row blocks
  const int nrb = (N + 127) / 128;
  const int gemm_blocks = ((nrb + 7) / 8) * 16;
  const int wb = (N + 3) / 4;  // one wave per node

  hipMemsetAsync(cnt, 0, (size_t)N * 64, stream);  // line-padded counters
  k_prep_hist<<<eb + 384 + xcb, 256, 0, stream>>>(
      W1, W2, w1t, w2t, dstv, cnt, pe, E, x, xb, ng);
  k_gemm1_scatter<<<gemm_blocks + eb4, 256, 0, stream>>>(
      xb, w1t, h8, N, as1, ad1, a_s1, a_d1,
      srcv, dstv, pe, col2, E, gemm_blocks);
  k_aggr<1><<<wb, 256, 0, stream>>>(h8, cnt, col2, a_s1, a_d1, b1,
                                    hb, nullptr, N);
  k_gemm2<<<gemm_blocks, 256, 0, stream>>>(hb, w2t, h8, N,
                                           as2, ad2, a_s2, a_d2);
  k_aggr<2><<<wb, 256, 0, stream>>>(h8, cnt, col2, a_s2, a_d2, b2,
                                    nullptr, out, N);
}